// Round 10
// baseline (102.607 us; speedup 1.0000x reference)
//
#include <hip/hip_runtime.h>

#define HH 64
#define WW 64
#define TT 16
#define NPIX (HH * WW * TT)   // 65536
#define TH 2                  // tile h
#define TW 4                  // tile w
#define HALO_H (TH + 6)       // 8
#define HALO_W (TW + 6)       // 10
#define CH_SZ (HALO_H * HALO_W * TT)   // 1280 floats/channel
#define NCH 15                // gui(9)+est(3)+var(3) staged; img stays global

// lane i <- lane i-1 within 16-lane DPP rows (row_shr:1), 0-fill at row start.
__device__ __forceinline__ float dpp_up1(float x) {
    return __int_as_float(__builtin_amdgcn_update_dpp(
        0, __float_as_int(x), 0x111, 0xF, 0xF, true));
}
// lane i <- lane i+1 within 16-lane DPP rows (row_shl:1), 0-fill at row end.
__device__ __forceinline__ float dpp_dn1(float x) {
    return __int_as_float(__builtin_amdgcn_update_dpp(
        0, __float_as_int(x), 0x101, 0xF, 0xF, true));
}

// Round-9 staged structure at 2x the occupancy: tile 2x4x16, halo 8x10x16,
// 76.8 KB LDS -> 2 blocks/CU x 16 waves = 32 waves/CU (8/SIMD). LDS staging
// keeps FETCH compulsory-only regardless of residency (the round-4/8 L2
// thrash can't return); 8 waves/SIMD hides the dependency stalls that kept
// VALUBusy at ~40% for rounds 3/6/9 (all 4 waves/SIMD, all ~29 us).
// Wave = 8 tile-pixels x 8 t-groups, t={2tg,2tg+1} float2 + DPP t-halo;
// 16 column-splits (wave s: columns r = s + 16i < 49).
__global__ __launch_bounds__(1024, 8) void statdenoise_kernel(
    const float* __restrict__ img,
    const float* __restrict__ gui,
    const float* __restrict__ est,
    const float* __restrict__ var,
    float* __restrict__ out)
{
    __shared__ float smem[NCH * CH_SZ];   // 76.8 KB; aliased by reduction later

    const float SIG[9] = {0.1f, 0.1f, 0.1f, 50.0f, 50.0f, 50.0f, 10.0f, 10.0f, 10.0f};
    const float G2 = 2.907f * 2.907f;   // gamma^2

    const int tid  = threadIdx.x;
    const int lane = tid & 63;
    const int s    = tid >> 6;      // wave id == column-split 0..15
    const int tg   = lane & 7;      // t-group 0..7
    const int hwl  = lane >> 3;     // tile pixel 0..7
    const int t0   = tg * 2;        // owns t0, t0+1
    const int h0   = (blockIdx.x >> 4) << 1;   // 32 h-tiles x 2 rows
    const int w0   = (blockIdx.x & 15) << 2;   // 16 w-tiles x 4 cols

    // ---- stage 15 channels of the 8x10x16 halo (edge-clamped; OOB masked
    //      later by inb, same semantics as the clamped global loads) ----
#pragma unroll
    for (int rep = 0; rep < 2; ++rep) {
        const int q = tid + rep * 1024;
        if (q < CH_SZ) {
            const int t   = q & 15;
            const int hwq = q >> 4;                  // 0..79
            const int hq  = (hwq * 205) >> 11;       // exact /10 for hwq<1024
            const int wq  = hwq - hq * 10;
            const int hs  = min(max(h0 - 3 + hq, 0), HH - 1);
            const int ws  = min(max(w0 - 3 + wq, 0), WW - 1);
            const int g   = (((hs << 6) + ws) << 4) + t;
#pragma unroll
            for (int c = 0; c < 9; ++c) smem[c * CH_SZ + q] = gui[c * NPIX + g];
#pragma unroll
            for (int c = 0; c < 3; ++c) {
                smem[(9 + c)  * CH_SZ + q] = est[c * NPIX + g];
                smem[(12 + c) * CH_SZ + q] = var[c * NPIX + g];
            }
        }
    }
    __syncthreads();

    const int th = hwl >> 2, tw = hwl & 3;     // tile-local pixel
    const int hg = h0 + th,  wg = w0 + tw;     // global pixel

    // center values from LDS
    const int rowc = (th + 3) * 10 + (tw + 3);
    const int lc = rowc * 16 + t0;
    float2 gc[9];
#pragma unroll
    for (int c = 0; c < 9; ++c) gc[c] = *(const float2*)&smem[c * CH_SZ + lc];
    float2 ec[3], vc[3];
#pragma unroll
    for (int c = 0; c < 3; ++c) {
        ec[c] = *(const float2*)&smem[(9 + c)  * CH_SZ + lc];
        vc[c] = *(const float2*)&smem[(12 + c) * CH_SZ + lc];
    }

    const bool vLo = (t0 != 0);    // dt=-1 valid; also masks DPP boundary garbage
    const bool vHi = (t0 != 14);   // dt=+1 valid; also masks DPP boundary garbage

    float acc[2][4] = {};   // per owned t: {r,g,b,wsum}

    int dh = s / 7 - 3, dw = s % 7 - 3;   // column r = s, then += 16
    for (int r = s; r < 49; r += 16) {
        // halo coords always in range: th+dh+3 in [0,7], tw+dw+3 in [0,9]
        const int lb  = (rowc + dh * 10 + dw) * 16 + t0;
        const bool inb = ((unsigned)(hg + dh) < (unsigned)HH) &
                         ((unsigned)(wg + dw) < (unsigned)WW);
        // clamped global offset for img
        const int hhc = min(max(hg + dh, 0), HH - 1);
        const int wwc = min(max(wg + dw, 0), WW - 1);
        const int gnb = (((hhc << 6) + wwc) << 4) + t0;

        // ---- bilateral over 9 guidance channels, 6 (e,dt) pairs ----
        float sb[2][3] = {};
#pragma unroll
        for (int c = 0; c < 9; ++c) {
            float2 m = *(const float2*)&smem[c * CH_SZ + lb];
            float nv[4] = {dpp_up1(m.y), m.x, m.y, dpp_dn1(m.x)};  // t0-1..t0+2
#pragma unroll
            for (int e = 0; e < 2; ++e) {
                float ce = e ? gc[c].y : gc[c].x;
#pragma unroll
                for (int k = 0; k < 3; ++k) {
                    float d = ce - nv[e + k];
                    sb[e][k] = fmaf(d * d, SIG[c], sb[e][k]);
                }
            }
        }

        // ---- membership (division-free Welch t-test) ----
        // (OOB h/w neighbors provably get weight 0 in the reference -> masked
        //  by inb; center pair passes naturally: d2==0.)
        bool mem[2][3] = {{true, true, true}, {true, true, true}};
#pragma unroll
        for (int c = 0; c < 3; ++c) {
            float2 em = *(const float2*)&smem[(9 + c)  * CH_SZ + lb];
            float2 vm = *(const float2*)&smem[(12 + c) * CH_SZ + lb];
            float env[4] = {dpp_up1(em.y), em.x, em.y, dpp_dn1(em.x)};
            float vnv[4] = {dpp_up1(vm.y), vm.x, vm.y, dpp_dn1(vm.x)};
#pragma unroll
            for (int e = 0; e < 2; ++e) {
                float ece = e ? ec[c].y : ec[c].x;
                float vce = e ? vc[c].y : vc[c].x;
#pragma unroll
                for (int k = 0; k < 3; ++k) {
                    float d  = ece - env[e + k];
                    float d2 = d * d;
                    float V  = vce + vnv[e + k];
                    bool pass = (d2 < G2 * V) | ((d2 == 0.f) & (V == 0.f));
                    bool kill = ((vce == 0.f) | (vnv[e + k] == 0.f)) & (d2 != 0.f);
                    mem[e][k] = mem[e][k] & pass & (!kill);
                }
            }
        }

        // ---- weights ----
        float wt[2][3];
#pragma unroll
        for (int e = 0; e < 2; ++e) {
#pragma unroll
            for (int k = 0; k < 3; ++k) {
                bool ok = inb && mem[e][k];
                if (e == 0 && k == 0) ok = ok && vLo;   // tt = t0-1
                if (e == 1 && k == 2) ok = ok && vHi;   // tt = t0+2
                wt[e][k] = ok ? __expf(-0.5f * sb[e][k]) : 0.f;
            }
        }

        // ---- accumulate image (global; consumed last, latency hidden) ----
#pragma unroll
        for (int c = 0; c < 3; ++c) {
            float2 im = *(const float2*)&img[c * NPIX + gnb];
            float iv[4] = {dpp_up1(im.y), im.x, im.y, dpp_dn1(im.x)};
#pragma unroll
            for (int e = 0; e < 2; ++e) {
                acc[e][c] = fmaf(wt[e][0], iv[e],
                            fmaf(wt[e][1], iv[e + 1],
                            fmaf(wt[e][2], iv[e + 2], acc[e][c])));
            }
        }
#pragma unroll
        for (int e = 0; e < 2; ++e)
            acc[e][3] += wt[e][0] + wt[e][1] + wt[e][2];

        dw += 16;
        while (dw > 3) { dw -= 7; ++dh; }
    }

    // ---- combine the 16 splits (alias staging LDS after all reads done) ----
    __syncthreads();
    float4* red = (float4*)smem;          // 16*64*2 float4 = 32 KB < 76.8 KB
    red[(s * 64 + lane) * 2 + 0] = make_float4(acc[0][0], acc[0][1], acc[0][2], acc[0][3]);
    red[(s * 64 + lane) * 2 + 1] = make_float4(acc[1][0], acc[1][1], acc[1][2], acc[1][3]);
    __syncthreads();

    if (tid < 128) {
        const int hwl_ = tid >> 4;          // tile pixel 0..7
        const int tloc = tid & 15;          // t 0..15
        const int tg_  = tloc >> 1, e_ = tloc & 1;
        float4 sum = make_float4(0.f, 0.f, 0.f, 0.f);
#pragma unroll
        for (int q = 0; q < 16; ++q) {
            float4 v = red[(q * 64 + hwl_ * 8 + tg_) * 2 + e_];
            sum.x += v.x; sum.y += v.y; sum.z += v.z; sum.w += v.w;
        }
        const int th_ = hwl_ >> 2, tw_ = hwl_ & 3;
        const int px = ((((h0 + th_) << 6) + (w0 + tw_)) << 4) + tloc;
        const float inv = 1.f / sum.w;      // wsum >= 1 (center weight == 1)
        out[0 * NPIX + px] = sum.x * inv;
        out[1 * NPIX + px] = sum.y * inv;
        out[2 * NPIX + px] = sum.z * inv;
    }
}

extern "C" void kernel_launch(void* const* d_in, const int* in_sizes, int n_in,
                              void* d_out, int out_size, void* d_ws, size_t ws_size,
                              hipStream_t stream) {
    const float* img = (const float*)d_in[0];
    const float* gui = (const float*)d_in[1];
    const float* est = (const float*)d_in[2];
    const float* var = (const float*)d_in[3];
    float* out = (float*)d_out;

    dim3 grid(512);     // 32 h-tiles x 16 w-tiles, 2 blocks/CU
    dim3 block(1024);   // 16 waves = 16 column-splits
    statdenoise_kernel<<<grid, block, 0, stream>>>(img, gui, est, var, out);
}

// Round 11
// 56.740 us; speedup vs baseline: 1.8084x; 1.8084x over previous
//
#include <hip/hip_runtime.h>

#define HH 64
#define WW 64
#define TT 16
#define NPIX (HH * WW * TT)   // 65536
#define HALO 10               // 4 + 2*3
#define HWH  (HALO * HALO)    // 100 halo (h,w) positions
#define CH_SZ (HWH * TT)      // 1600 floats per channel
#define NCH 18                // gui(9) + est(3) + var(3) + img(3) ALL staged

// lane i <- lane i-1 within 16-lane DPP rows (row_shr:1), 0-fill at row start.
__device__ __forceinline__ float dpp_up1(float x) {
    return __int_as_float(__builtin_amdgcn_update_dpp(
        0, __float_as_int(x), 0x111, 0xF, 0xF, true));
}
// lane i <- lane i+1 within 16-lane DPP rows (row_shl:1), 0-fill at row end.
__device__ __forceinline__ float dpp_dn1(float x) {
    return __int_as_float(__builtin_amdgcn_update_dpp(
        0, __float_as_int(x), 0x101, 0xF, 0xF, true));
}

// 256 blocks (1/CU, LDS-enforced: 115.2 KB so 2 blocks can't co-reside ->
// per-XCD footprint stays < L2 by construction; rounds 4/8/10 proved any
// >=2-block/CU residency thrashes the 4 MiB per-XCD L2 at ~2 TB/s).
// Tile 4x4x16, halo 10x10x16, ALL 18 channels staged once -> K-loop is
// pure LDS+VALU. K=4 t-blocking: lane = hw*4+tg (16 hw x 4 tg), each lane
// owns t={4tg..4tg+3} via one float4/channel/column; ONE wave covers the
// whole tile per column -> 49 columns over 16 waves, 12 independent pairs
// per lane per column (2x R9's ILP, half its per-pair overhead).
// t-halo via +-1-lane DPP: garbage only at tg=0 (t0-1<0) / tg=3 (t0+4>15),
// exactly the OOB-masked pairs.
__global__ __launch_bounds__(1024) void statdenoise_kernel(
    const float* __restrict__ img,
    const float* __restrict__ gui,
    const float* __restrict__ est,
    const float* __restrict__ var,
    float* __restrict__ out)
{
    __shared__ float smem[NCH * CH_SZ];   // 115.2 KB; aliased by reduction later

    const float SIG[9] = {0.1f, 0.1f, 0.1f, 50.0f, 50.0f, 50.0f, 10.0f, 10.0f, 10.0f};
    const float G2 = 2.907f * 2.907f;   // gamma^2

    const int tid  = threadIdx.x;
    const int lane = tid & 63;
    const int s    = tid >> 6;      // wave id == column-split 0..15
    const int tg   = lane & 3;      // t-group 0..3
    const int hwl  = lane >> 2;     // tile pixel 0..15
    const int t0   = tg * 4;        // owns t0..t0+3
    const int h0   = (blockIdx.x >> 4) << 2;   // 16x16 tiles of 4x4
    const int w0   = (blockIdx.x & 15) << 2;

    // ---- stage all 18 channels of the 10x10x16 halo (edge-clamped; OOB
    //      pairs masked later by inb, same semantics as clamped loads) ----
#pragma unroll
    for (int rep = 0; rep < 2; ++rep) {
        const int q = tid + rep * 1024;
        if (q < CH_SZ) {
            const int t   = q & 15;
            const int hwq = q >> 4;                  // 0..99
            const int hq  = (hwq * 205) >> 11;       // exact /10 for hwq<1024
            const int wq  = hwq - hq * 10;
            const int hs  = min(max(h0 - 3 + hq, 0), HH - 1);
            const int ws  = min(max(w0 - 3 + wq, 0), WW - 1);
            const int g   = (((hs << 6) + ws) << 4) + t;
#pragma unroll
            for (int c = 0; c < 9; ++c) smem[c * CH_SZ + q] = gui[c * NPIX + g];
#pragma unroll
            for (int c = 0; c < 3; ++c) {
                smem[(9 + c)  * CH_SZ + q] = est[c * NPIX + g];
                smem[(12 + c) * CH_SZ + q] = var[c * NPIX + g];
                smem[(15 + c) * CH_SZ + q] = img[c * NPIX + g];
            }
        }
    }
    __syncthreads();

    const int th = hwl >> 2, tw = hwl & 3;     // tile-local pixel
    const int hg = h0 + th,  wg = w0 + tw;     // global pixel

    // center values from LDS (float4 along t)
    const int rowc = (th + 3) * 10 + (tw + 3);
    const int lc = rowc * 16 + t0;
    float4 gc[9];
#pragma unroll
    for (int c = 0; c < 9; ++c) gc[c] = *(const float4*)&smem[c * CH_SZ + lc];
    float4 ec[3], vc[3];
#pragma unroll
    for (int c = 0; c < 3; ++c) {
        ec[c] = *(const float4*)&smem[(9 + c)  * CH_SZ + lc];
        vc[c] = *(const float4*)&smem[(12 + c) * CH_SZ + lc];
    }

    const bool vLo = (t0 != 0);     // pair (e=0,k=0): t0-1  (also DPP garbage mask)
    const bool vHi = (t0 != 12);    // pair (e=3,k=2): t0+4  (also DPP garbage mask)

    float acc[4][4] = {};   // per owned t: {r,g,b,wsum}

    int dh = s / 7 - 3, dw = s % 7 - 3;   // column r = s, then += 16
    for (int r = s; r < 49; r += 16) {
        // halo coords always in range: th+dh+3 in [0,9], tw+dw+3 in [0,9]
        const int lb  = (rowc + dh * 10 + dw) * 16 + t0;
        const bool inb = ((unsigned)(hg + dh) < (unsigned)HH) &
                         ((unsigned)(wg + dw) < (unsigned)WW);

        // ---- bilateral over 9 guidance channels, 12 (e,dt) pairs ----
        float sb[4][3] = {};
#pragma unroll
        for (int c = 0; c < 9; ++c) {
            float4 m = *(const float4*)&smem[c * CH_SZ + lb];
            float nv[6] = {dpp_up1(m.w), m.x, m.y, m.z, m.w, dpp_dn1(m.x)};
            float ce[4] = {gc[c].x, gc[c].y, gc[c].z, gc[c].w};
#pragma unroll
            for (int e = 0; e < 4; ++e) {
#pragma unroll
                for (int k = 0; k < 3; ++k) {        // neighbor t = t0+e+k-1
                    float d = ce[e] - nv[e + k];
                    sb[e][k] = fmaf(d * d, SIG[c], sb[e][k]);
                }
            }
        }

        // ---- membership (division-free Welch t-test) ----
        // (OOB h/w neighbors provably get weight 0 in the reference -> inb;
        //  center pair passes naturally: d2==0.)
        bool mem[4][3] = {{1,1,1},{1,1,1},{1,1,1},{1,1,1}};
#pragma unroll
        for (int c = 0; c < 3; ++c) {
            float4 em = *(const float4*)&smem[(9 + c)  * CH_SZ + lb];
            float4 vm = *(const float4*)&smem[(12 + c) * CH_SZ + lb];
            float env[6] = {dpp_up1(em.w), em.x, em.y, em.z, em.w, dpp_dn1(em.x)};
            float vnv[6] = {dpp_up1(vm.w), vm.x, vm.y, vm.z, vm.w, dpp_dn1(vm.x)};
            float ece[4] = {ec[c].x, ec[c].y, ec[c].z, ec[c].w};
            float vce[4] = {vc[c].x, vc[c].y, vc[c].z, vc[c].w};
#pragma unroll
            for (int e = 0; e < 4; ++e) {
#pragma unroll
                for (int k = 0; k < 3; ++k) {
                    float d  = ece[e] - env[e + k];
                    float d2 = d * d;
                    float V  = vce[e] + vnv[e + k];
                    bool pass = (d2 < G2 * V) | ((d2 == 0.f) & (V == 0.f));
                    bool kill = ((vce[e] == 0.f) | (vnv[e + k] == 0.f)) & (d2 != 0.f);
                    mem[e][k] = mem[e][k] & pass & (!kill);
                }
            }
        }

        // ---- weights ----
        float wt[4][3];
#pragma unroll
        for (int e = 0; e < 4; ++e) {
#pragma unroll
            for (int k = 0; k < 3; ++k) {
                bool ok = inb && mem[e][k];
                if (e == 0 && k == 0) ok = ok && vLo;   // t0-1
                if (e == 3 && k == 2) ok = ok && vHi;   // t0+4
                wt[e][k] = ok ? __expf(-0.5f * sb[e][k]) : 0.f;
            }
        }

        // ---- accumulate image (from LDS) ----
#pragma unroll
        for (int c = 0; c < 3; ++c) {
            float4 im = *(const float4*)&smem[(15 + c) * CH_SZ + lb];
            float iv[6] = {dpp_up1(im.w), im.x, im.y, im.z, im.w, dpp_dn1(im.x)};
#pragma unroll
            for (int e = 0; e < 4; ++e) {
                acc[e][c] = fmaf(wt[e][0], iv[e],
                            fmaf(wt[e][1], iv[e + 1],
                            fmaf(wt[e][2], iv[e + 2], acc[e][c])));
            }
        }
#pragma unroll
        for (int e = 0; e < 4; ++e)
            acc[e][3] += wt[e][0] + wt[e][1] + wt[e][2];

        dw += 16;
        while (dw > 3) { dw -= 7; ++dh; }
    }

    // ---- combine the 16 splits (alias staging LDS after all reads done) ----
    __syncthreads();
    float4* red = (float4*)smem;          // 16*64*4 float4 = 64 KB < 115.2 KB
#pragma unroll
    for (int e = 0; e < 4; ++e)
        red[(s * 64 + lane) * 4 + e] = make_float4(acc[e][0], acc[e][1], acc[e][2], acc[e][3]);
    __syncthreads();

    if (tid < 256) {
        const int hw_ = tid >> 4;           // tile pixel 0..15
        const int t_  = tid & 15;           // t 0..15
        const int tg_ = t_ >> 2, e_ = t_ & 3;
        const int li  = hw_ * 4 + tg_;      // lane that owns this (hw, t0) group
        float4 sum = make_float4(0.f, 0.f, 0.f, 0.f);
#pragma unroll
        for (int q = 0; q < 16; ++q) {
            float4 v = red[(q * 64 + li) * 4 + e_];
            sum.x += v.x; sum.y += v.y; sum.z += v.z; sum.w += v.w;
        }
        const int th_ = hw_ >> 2, tw_ = hw_ & 3;
        const int px = ((((h0 + th_) << 6) + (w0 + tw_)) << 4) + t_;
        const float inv = 1.f / sum.w;      // wsum >= 1 (center weight == 1)
        out[0 * NPIX + px] = sum.x * inv;
        out[1 * NPIX + px] = sum.y * inv;
        out[2 * NPIX + px] = sum.z * inv;
    }
}

extern "C" void kernel_launch(void* const* d_in, const int* in_sizes, int n_in,
                              void* d_out, int out_size, void* d_ws, size_t ws_size,
                              hipStream_t stream) {
    const float* img = (const float*)d_in[0];
    const float* gui = (const float*)d_in[1];
    const float* est = (const float*)d_in[2];
    const float* var = (const float*)d_in[3];
    float* out = (float*)d_out;

    dim3 grid(256);     // 16x16 tiles of 4x4x16, 1 block per CU (LDS-enforced)
    dim3 block(1024);   // 16 waves = 16 column-splits; wave covers whole tile
    statdenoise_kernel<<<grid, block, 0, stream>>>(img, gui, est, var, out);
}

// Round 12
// 31.685 us; speedup vs baseline: 3.2383x; 1.7907x over previous
//
#include <hip/hip_runtime.h>

#define HH 64
#define WW 64
#define TT 16
#define NPIX (HH * WW * TT)   // 65536
#define HALO 10               // 4 + 2*3
#define HWH  (HALO * HALO)    // 100 halo (h,w) positions
#define CH_SZ (HWH * TT)      // 1600 floats per channel
#define NCH 18                // gui(9) + est(3) + var(3) + img(3) ALL staged

// lane i <- lane i-1 within 16-lane DPP rows (row_shr:1), 0-fill at row start.
__device__ __forceinline__ float dpp_up1(float x) {
    return __int_as_float(__builtin_amdgcn_update_dpp(
        0, __float_as_int(x), 0x111, 0xF, 0xF, true));
}
// lane i <- lane i+1 within 16-lane DPP rows (row_shl:1), 0-fill at row end.
__device__ __forceinline__ float dpp_dn1(float x) {
    return __int_as_float(__builtin_amdgcn_update_dpp(
        0, __float_as_int(x), 0x101, 0xF, 0xF, true));
}

// Round-11 structure at 512 threads: the 1024-thread version hard-capped
// VGPR at 64 while the K=4 body needs ~115 -> scratch spill (WRITE_SIZE
// 104 MB, 56.7 us). 512 threads = 8 waves => VGPR cap 256, zero spill.
// 256 blocks (1/CU, LDS-enforced: 115.2 KB). Tile 4x4x16, halo 10x10x16,
// all 18 channels staged once -> K-loop is pure LDS+VALU, no barriers.
// K=4 t-blocking: lane = hw*4+tg (16 hw x 4 tg), each lane owns t=
// {4tg..4tg+3} via one float4/channel/column; ONE wave covers the whole
// tile per column -> 49 columns over 8 waves, 12 independent pairs per
// lane per column (ILP covers LDS latency at 2 waves/SIMD).
// t-halo via +-1-lane DPP: garbage only at tg=0 (t0-1<0) / tg=3 (t0+4>15),
// exactly the OOB-masked pairs.
__global__ __launch_bounds__(512, 2) void statdenoise_kernel(
    const float* __restrict__ img,
    const float* __restrict__ gui,
    const float* __restrict__ est,
    const float* __restrict__ var,
    float* __restrict__ out)
{
    __shared__ float smem[NCH * CH_SZ];   // 115.2 KB; aliased by reduction later

    const float SIG[9] = {0.1f, 0.1f, 0.1f, 50.0f, 50.0f, 50.0f, 10.0f, 10.0f, 10.0f};
    const float G2 = 2.907f * 2.907f;   // gamma^2

    const int tid  = threadIdx.x;
    const int lane = tid & 63;
    const int s    = tid >> 6;      // wave id == column-split 0..7
    const int tg   = lane & 3;      // t-group 0..3
    const int hwl  = lane >> 2;     // tile pixel 0..15
    const int t0   = tg * 4;        // owns t0..t0+3
    const int h0   = (blockIdx.x >> 4) << 2;   // 16x16 tiles of 4x4
    const int w0   = (blockIdx.x & 15) << 2;

    // ---- stage all 18 channels of the 10x10x16 halo (edge-clamped; OOB
    //      pairs masked later by inb, same semantics as clamped loads) ----
#pragma unroll
    for (int rep = 0; rep < 4; ++rep) {
        const int q = tid + rep * 512;
        if (q < CH_SZ) {
            const int t   = q & 15;
            const int hwq = q >> 4;                  // 0..99
            const int hq  = (hwq * 205) >> 11;       // exact /10 for hwq<1024
            const int wq  = hwq - hq * 10;
            const int hs  = min(max(h0 - 3 + hq, 0), HH - 1);
            const int ws  = min(max(w0 - 3 + wq, 0), WW - 1);
            const int g   = (((hs << 6) + ws) << 4) + t;
#pragma unroll
            for (int c = 0; c < 9; ++c) smem[c * CH_SZ + q] = gui[c * NPIX + g];
#pragma unroll
            for (int c = 0; c < 3; ++c) {
                smem[(9 + c)  * CH_SZ + q] = est[c * NPIX + g];
                smem[(12 + c) * CH_SZ + q] = var[c * NPIX + g];
                smem[(15 + c) * CH_SZ + q] = img[c * NPIX + g];
            }
        }
    }
    __syncthreads();

    const int th = hwl >> 2, tw = hwl & 3;     // tile-local pixel
    const int hg = h0 + th,  wg = w0 + tw;     // global pixel

    // center values from LDS (float4 along t)
    const int rowc = (th + 3) * 10 + (tw + 3);
    const int lc = rowc * 16 + t0;
    float4 gc[9];
#pragma unroll
    for (int c = 0; c < 9; ++c) gc[c] = *(const float4*)&smem[c * CH_SZ + lc];
    float4 ec[3], vc[3];
#pragma unroll
    for (int c = 0; c < 3; ++c) {
        ec[c] = *(const float4*)&smem[(9 + c)  * CH_SZ + lc];
        vc[c] = *(const float4*)&smem[(12 + c) * CH_SZ + lc];
    }

    const bool vLo = (t0 != 0);     // pair (e=0,k=0): t0-1  (also DPP garbage mask)
    const bool vHi = (t0 != 12);    // pair (e=3,k=2): t0+4  (also DPP garbage mask)

    float acc[4][4] = {};   // per owned t: {r,g,b,wsum}

    int dh = s / 7 - 3, dw = s % 7 - 3;   // column r = s, then += 8
    for (int r = s; r < 49; r += 8) {
        // halo coords always in range: th+dh+3 in [0,9], tw+dw+3 in [0,9]
        const int lb  = (rowc + dh * 10 + dw) * 16 + t0;
        const bool inb = ((unsigned)(hg + dh) < (unsigned)HH) &
                         ((unsigned)(wg + dw) < (unsigned)WW);

        // ---- bilateral over 9 guidance channels, 12 (e,dt) pairs ----
        float sb[4][3] = {};
#pragma unroll
        for (int c = 0; c < 9; ++c) {
            float4 m = *(const float4*)&smem[c * CH_SZ + lb];
            float nv[6] = {dpp_up1(m.w), m.x, m.y, m.z, m.w, dpp_dn1(m.x)};
            float ce[4] = {gc[c].x, gc[c].y, gc[c].z, gc[c].w};
#pragma unroll
            for (int e = 0; e < 4; ++e) {
#pragma unroll
                for (int k = 0; k < 3; ++k) {        // neighbor t = t0+e+k-1
                    float d = ce[e] - nv[e + k];
                    sb[e][k] = fmaf(d * d, SIG[c], sb[e][k]);
                }
            }
        }

        // ---- membership (division-free Welch t-test) ----
        // (OOB h/w neighbors provably get weight 0 in the reference -> inb;
        //  center pair passes naturally: d2==0.)
        bool mem[4][3] = {{1,1,1},{1,1,1},{1,1,1},{1,1,1}};
#pragma unroll
        for (int c = 0; c < 3; ++c) {
            float4 em = *(const float4*)&smem[(9 + c)  * CH_SZ + lb];
            float4 vm = *(const float4*)&smem[(12 + c) * CH_SZ + lb];
            float env[6] = {dpp_up1(em.w), em.x, em.y, em.z, em.w, dpp_dn1(em.x)};
            float vnv[6] = {dpp_up1(vm.w), vm.x, vm.y, vm.z, vm.w, dpp_dn1(vm.x)};
            float ece[4] = {ec[c].x, ec[c].y, ec[c].z, ec[c].w};
            float vce[4] = {vc[c].x, vc[c].y, vc[c].z, vc[c].w};
#pragma unroll
            for (int e = 0; e < 4; ++e) {
#pragma unroll
                for (int k = 0; k < 3; ++k) {
                    float d  = ece[e] - env[e + k];
                    float d2 = d * d;
                    float V  = vce[e] + vnv[e + k];
                    bool pass = (d2 < G2 * V) | ((d2 == 0.f) & (V == 0.f));
                    bool kill = ((vce[e] == 0.f) | (vnv[e + k] == 0.f)) & (d2 != 0.f);
                    mem[e][k] = mem[e][k] & pass & (!kill);
                }
            }
        }

        // ---- weights ----
        float wt[4][3];
#pragma unroll
        for (int e = 0; e < 4; ++e) {
#pragma unroll
            for (int k = 0; k < 3; ++k) {
                bool ok = inb && mem[e][k];
                if (e == 0 && k == 0) ok = ok && vLo;   // t0-1
                if (e == 3 && k == 2) ok = ok && vHi;   // t0+4
                wt[e][k] = ok ? __expf(-0.5f * sb[e][k]) : 0.f;
            }
        }

        // ---- accumulate image (from LDS) ----
#pragma unroll
        for (int c = 0; c < 3; ++c) {
            float4 im = *(const float4*)&smem[(15 + c) * CH_SZ + lb];
            float iv[6] = {dpp_up1(im.w), im.x, im.y, im.z, im.w, dpp_dn1(im.x)};
#pragma unroll
            for (int e = 0; e < 4; ++e) {
                acc[e][c] = fmaf(wt[e][0], iv[e],
                            fmaf(wt[e][1], iv[e + 1],
                            fmaf(wt[e][2], iv[e + 2], acc[e][c])));
            }
        }
#pragma unroll
        for (int e = 0; e < 4; ++e)
            acc[e][3] += wt[e][0] + wt[e][1] + wt[e][2];

        dw += 8;
        while (dw > 3) { dw -= 7; ++dh; }
    }

    // ---- combine the 8 splits (alias staging LDS after all reads done) ----
    __syncthreads();
    float4* red = (float4*)smem;          // 8*64*4 float4 = 32 KB < 115.2 KB
#pragma unroll
    for (int e = 0; e < 4; ++e)
        red[(s * 64 + lane) * 4 + e] = make_float4(acc[e][0], acc[e][1], acc[e][2], acc[e][3]);
    __syncthreads();

    if (tid < 256) {
        const int hw_ = tid >> 4;           // tile pixel 0..15
        const int t_  = tid & 15;           // t 0..15
        const int tg_ = t_ >> 2, e_ = t_ & 3;
        const int li  = hw_ * 4 + tg_;      // lane that owns this (hw, t0) group
        float4 sum = make_float4(0.f, 0.f, 0.f, 0.f);
#pragma unroll
        for (int q = 0; q < 8; ++q) {
            float4 v = red[(q * 64 + li) * 4 + e_];
            sum.x += v.x; sum.y += v.y; sum.z += v.z; sum.w += v.w;
        }
        const int th_ = hw_ >> 2, tw_ = hw_ & 3;
        const int px = ((((h0 + th_) << 6) + (w0 + tw_)) << 4) + t_;
        const float inv = 1.f / sum.w;      // wsum >= 1 (center weight == 1)
        out[0 * NPIX + px] = sum.x * inv;
        out[1 * NPIX + px] = sum.y * inv;
        out[2 * NPIX + px] = sum.z * inv;
    }
}

extern "C" void kernel_launch(void* const* d_in, const int* in_sizes, int n_in,
                              void* d_out, int out_size, void* d_ws, size_t ws_size,
                              hipStream_t stream) {
    const float* img = (const float*)d_in[0];
    const float* gui = (const float*)d_in[1];
    const float* est = (const float*)d_in[2];
    const float* var = (const float*)d_in[3];
    float* out = (float*)d_out;

    dim3 grid(256);     // 16x16 tiles of 4x4x16, 1 block per CU (LDS-enforced)
    dim3 block(512);    // 8 waves = 8 column-splits; wave covers whole tile
    statdenoise_kernel<<<grid, block, 0, stream>>>(img, gui, est, var, out);
}